// Round 3
// baseline (484.741 us; speedup 1.0000x reference)
//
#include <hip/hip_runtime.h>
#include <cstdint>
#include <cstddef>

#define NN 8192
#define FIN 128
#define FOUT 64

typedef __attribute__((ext_vector_type(8))) short short8;
typedef __attribute__((ext_vector_type(4))) float f32x4;

__device__ __forceinline__ unsigned short f32_to_bf16_bits(float f) {
    union { float f; uint32_t u; } c; c.f = f;
    uint32_t u = c.u;
    u += 0x7fffu + ((u >> 16) & 1u);   // RNE
    return (unsigned short)(u >> 16);
}

__device__ __forceinline__ unsigned int pack_bf16(float lo, float hi) {
    return (unsigned int)f32_to_bf16_bits(lo) |
           ((unsigned int)f32_to_bf16_bits(hi) << 16);
}

// Kernel 0: compress adj (int32 0/1) -> bitmask, 32 entries per word.
// Per-thread 128 B contiguous reads (linear stream, ~6.3 TB/s pattern);
// 268 MB -> 8.4 MB so gat_attn never touches adj's pathological layout.
__global__ __launch_bounds__(256) void gat_mask(
    const int* __restrict__ adj, unsigned int* __restrict__ maskW)
{
    const size_t t = (size_t)blockIdx.x * 256 + threadIdx.x;   // word index
    const int4* p = (const int4*)(adj + t * 32);
    unsigned int m = 0;
#pragma unroll
    for (int k = 0; k < 8; ++k) {
        int4 v = p[k];
        m |= (v.x > 0 ? 1u : 0u) << (k * 4 + 0);
        m |= (v.y > 0 ? 1u : 0u) << (k * 4 + 1);
        m |= (v.z > 0 ? 1u : 0u) << (k * 4 + 2);
        m |= (v.w > 0 ? 1u : 0u) << (k * 4 + 3);
    }
    maskW[t] = m;
}

// Kernel 1: Wh = x @ W^T (bf16, stored transposed [f][i]); Wh1 = Wh@a1; Wh2 = Wh@a2
__global__ __launch_bounds__(256) void gat_prep(
    const float* __restrict__ x, const float* __restrict__ W,
    const float* __restrict__ a, unsigned short* __restrict__ WhT,
    float* __restrict__ Wh1, float* __restrict__ Wh2)
{
    const int t    = threadIdx.x;
    const int f    = t & 63;        // lane = feature
    const int iloc = t >> 6;        // wave = local row
    const int i    = blockIdx.x * 4 + iloc;

    const float4* x4 = (const float4*)(x + (size_t)i * FIN);  // wave-uniform
    const float4* w4 = (const float4*)(W + (size_t)f * FIN);

    float acc = 0.f;
#pragma unroll
    for (int k = 0; k < FIN / 4; ++k) {
        float4 xv = x4[k];
        float4 wv = w4[k];
        acc += xv.x * wv.x + xv.y * wv.y + xv.z * wv.z + xv.w * wv.w;
    }

    WhT[(size_t)f * NN + i] = f32_to_bf16_bits(acc);

    float r1 = acc * a[f];
    float r2 = acc * a[64 + f];
#pragma unroll
    for (int m = 1; m < 64; m <<= 1) {
        r1 += __shfl_xor(r1, m, 64);
        r2 += __shfl_xor(r2, m, 64);
    }
    if (f == 0) { Wh1[i] = r1; Wh2[i] = r2; }
}

// Kernel 2: 1024 blocks = (512 row-tiles) x (2 j-halves), 4 waves each.
// All memory traffic is L2-resident (mask 8.4 MB, WhT 1 MB, Wh2 32 KB) ->
// compute-bound. Lanes build P directly in MFMA A-fragment layout.
// Writes PARTIAL C (16x64) + partial row-sums; combine kernel finishes.
__global__ __launch_bounds__(256, 4) void gat_attn(
    const unsigned int* __restrict__ maskW, const unsigned short* __restrict__ WhT,
    const float* __restrict__ Wh1, const float* __restrict__ Wh2,
    float* __restrict__ Cpart, float* __restrict__ Tpart)
{
    __shared__ float lds_C[4][16][68];   // +4 pad: breaks 4-way write conflict
    __shared__ float lds_tot[4][16];

    const int tid  = threadIdx.x;
    const int wave = tid >> 6;
    const int lane = tid & 63;
    const int il   = lane & 15;     // A-fragment row (i)
    const int q    = lane >> 4;     // quad -> k offset q*8
    const int rt   = blockIdx.x >> 1;
    const int jh   = blockIdx.x & 1;     // j-half
    const int i0   = rt * 16;
    const int i    = i0 + il;

    const float wh1   = Wh1[i];
    const int   jbase = jh * 4096 + wave * 32 + q * 8;
    const unsigned int* __restrict__ maskrow = maskW + (size_t)i * (NN / 32);
    const int wbase = jh * 128 + wave;   // mask word index base (+ tt*4)

    const short8* bp0 = (const short8*)(WhT + (size_t)(0  + il) * NN);
    const short8* bp1 = (const short8*)(WhT + (size_t)(16 + il) * NN);
    const short8* bp2 = (const short8*)(WhT + (size_t)(32 + il) * NN);
    const short8* bp3 = (const short8*)(WhT + (size_t)(48 + il) * NN);

    f32x4 acc0 = {0.f, 0.f, 0.f, 0.f};
    f32x4 acc1 = {0.f, 0.f, 0.f, 0.f};
    f32x4 acc2 = {0.f, 0.f, 0.f, 0.f};
    f32x4 acc3 = {0.f, 0.f, 0.f, 0.f};
    float tot = 0.f;

    for (int tt = 0; tt < 32; ++tt) {
        const int j = jbase + tt * 128;

        const unsigned int mw = maskrow[wbase + tt * 4];
        const unsigned int mb = mw >> (q * 8);   // 8 bits for this lane

        const float4 w20 = *(const float4*)(Wh2 + j);
        const float4 w21 = *(const float4*)(Wh2 + j + 4);

        float wv[8];
#define CALC(idx, wh2v)                                                \
        {                                                              \
            float s = wh1 + (wh2v);                                    \
            float e = fmaxf(s, 0.2f * s);      /* leaky_relu 0.2 */    \
            float v = ((mb >> idx) & 1u) ? __expf(e) : 0.f;            \
            tot += v;                                                  \
            wv[idx] = v;                                               \
        }
        CALC(0, w20.x) CALC(1, w20.y) CALC(2, w20.z) CALC(3, w20.w)
        CALC(4, w21.x) CALC(5, w21.y) CALC(6, w21.z) CALC(7, w21.w)
#undef CALC

        union { short8 v; unsigned int u[4]; } af;
        af.u[0] = pack_bf16(wv[0], wv[1]);
        af.u[1] = pack_bf16(wv[2], wv[3]);
        af.u[2] = pack_bf16(wv[4], wv[5]);
        af.u[3] = pack_bf16(wv[6], wv[7]);

        const int jb = j >> 3;
        const short8 b0 = bp0[jb];
        const short8 b1 = bp1[jb];
        const short8 b2 = bp2[jb];
        const short8 b3 = bp3[jb];

        acc0 = __builtin_amdgcn_mfma_f32_16x16x32_bf16(af.v, b0, acc0, 0, 0, 0);
        acc1 = __builtin_amdgcn_mfma_f32_16x16x32_bf16(af.v, b1, acc1, 0, 0, 0);
        acc2 = __builtin_amdgcn_mfma_f32_16x16x32_bf16(af.v, b2, acc2, 0, 0, 0);
        acc3 = __builtin_amdgcn_mfma_f32_16x16x32_bf16(af.v, b3, acc3, 0, 0, 0);
    }

    // row-total reduction: lanes {il, il+16, il+32, il+48} hold partials
    tot += __shfl_xor(tot, 16, 64);
    tot += __shfl_xor(tot, 32, 64);
    if (lane < 16) lds_tot[wave][lane] = tot;

    // C/D layout: col = lane&15 (f within tile), row = q*4 + reg (i)
#pragma unroll
    for (int r = 0; r < 4; ++r) {
        lds_C[wave][q * 4 + r][0 * 16 + il] = acc0[r];
        lds_C[wave][q * 4 + r][1 * 16 + il] = acc1[r];
        lds_C[wave][q * 4 + r][2 * 16 + il] = acc2[r];
        lds_C[wave][q * 4 + r][3 * 16 + il] = acc3[r];
    }
    __syncthreads();

#pragma unroll
    for (int e = 0; e < 4; ++e) {
        const int idx = e * 256 + tid;
        const int ii = idx >> 6;
        const int ff = idx & 63;
        float s = lds_C[0][ii][ff] + lds_C[1][ii][ff] +
                  lds_C[2][ii][ff] + lds_C[3][ii][ff];
        Cpart[((size_t)jh * NN + i0 + ii) * FOUT + ff] = s;
        if (ff == 0) {
            float ts = lds_tot[0][ii] + lds_tot[1][ii] +
                       lds_tot[2][ii] + lds_tot[3][ii];
            Tpart[(size_t)jh * NN + i0 + ii] = ts;
        }
    }
}

// Kernel 3: combine the two j-half partials, normalize, ELU.
__global__ __launch_bounds__(256) void gat_combine(
    const float* __restrict__ Cpart, const float* __restrict__ Tpart,
    float* __restrict__ out)
{
    const int idx = blockIdx.x * 256 + threadIdx.x;   // over NN*FOUT
    const int i = idx >> 6;                            // row
    const float c = Cpart[idx] + Cpart[(size_t)NN * FOUT + idx];
    const float t = Tpart[i] + Tpart[NN + i];
    const float p = c / t;
    out[idx] = (p > 0.f) ? p : (__expf(p) - 1.f);
}

extern "C" void kernel_launch(void* const* d_in, const int* in_sizes, int n_in,
                              void* d_out, int out_size, void* d_ws, size_t ws_size,
                              hipStream_t stream) {
    const float* x   = (const float*)d_in[0];
    const int*   adj = (const int*)d_in[1];
    const float* W   = (const float*)d_in[2];
    const float* a   = (const float*)d_in[3];
    float* out = (float*)d_out;

    char* ws = (char*)d_ws;
    unsigned short* WhT = (unsigned short*)ws;                 // 1 MB @ 0
    float* Wh1   = (float*)(ws + (size_t)1048576);             // 32 KB
    float* Wh2   = (float*)(ws + (size_t)1048576 + 32768);     // 32 KB
    float* Cpart = (float*)(ws + (size_t)2097152);             // 4 MB (2 halves)
    float* Tpart = (float*)(ws + (size_t)6291456);             // 64 KB
    unsigned int* maskW = (unsigned int*)(ws + (size_t)8388608); // 8 MB

    gat_mask<<<dim3((NN / 32) * NN / 256), dim3(256), 0, stream>>>(adj, maskW);
    gat_prep<<<dim3(NN / 4), dim3(256), 0, stream>>>(x, W, a, WhT, Wh1, Wh2);
    gat_attn<<<dim3(NN / 16 * 2), dim3(256), 0, stream>>>(maskW, WhT, Wh1, Wh2, Cpart, Tpart);
    gat_combine<<<dim3(NN * FOUT / 256), dim3(256), 0, stream>>>(Cpart, Tpart, out);
}

// Round 4
// 433.234 us; speedup vs baseline: 1.1189x; 1.1189x over previous
//
#include <hip/hip_runtime.h>
#include <cstdint>
#include <cstddef>

#define NN 8192
#define FIN 128
#define FOUT 64

typedef __attribute__((ext_vector_type(8))) short short8;
typedef __attribute__((ext_vector_type(4))) float f32x4;

__device__ __forceinline__ unsigned short f32_to_bf16_bits(float f) {
    union { float f; uint32_t u; } c; c.f = f;
    uint32_t u = c.u;
    u += 0x7fffu + ((u >> 16) & 1u);   // RNE
    return (unsigned short)(u >> 16);
}

__device__ __forceinline__ unsigned int pack_bf16(float lo, float hi) {
    return (unsigned int)f32_to_bf16_bits(lo) |
           ((unsigned int)f32_to_bf16_bits(hi) << 16);
}

// Kernel 1: Wh = x @ W^T (bf16, stored transposed [f][i]); Wh1 = Wh@a1; Wh2 = Wh@a2
__global__ __launch_bounds__(256) void gat_prep(
    const float* __restrict__ x, const float* __restrict__ W,
    const float* __restrict__ a, unsigned short* __restrict__ WhT,
    float* __restrict__ Wh1, float* __restrict__ Wh2)
{
    const int t    = threadIdx.x;
    const int f    = t & 63;        // lane = feature
    const int iloc = t >> 6;        // wave = local row
    const int i    = blockIdx.x * 4 + iloc;

    const float4* x4 = (const float4*)(x + (size_t)i * FIN);  // wave-uniform
    const float4* w4 = (const float4*)(W + (size_t)f * FIN);

    float acc = 0.f;
#pragma unroll
    for (int k = 0; k < FIN / 4; ++k) {
        float4 xv = x4[k];
        float4 wv = w4[k];
        acc += xv.x * wv.x + xv.y * wv.y + xv.z * wv.z + xv.w * wv.w;
    }

    WhT[(size_t)f * NN + i] = f32_to_bf16_bits(acc);

    float r1 = acc * a[f];
    float r2 = acc * a[64 + f];
#pragma unroll
    for (int m = 1; m < 64; m <<= 1) {
        r1 += __shfl_xor(r1, m, 64);
        r2 += __shfl_xor(r2, m, 64);
    }
    if (f == 0) { Wh1[i] = r1; Wh2[i] = r2; }
}

// Kernel 2: 512 blocks x 512 threads (8 waves); block = 16 rows x all 8192 cols.
// adj is read ONCE, streamed in 1024-col slabs via contiguous int4 loads
// (2x512B segments per instruction), packed to bytes, double-buffered in LDS.
// Compute lanes read their A-fragment mask bytes from LDS (swizzled, <=4-way).
// Epilogue reduces the 8 waves' partial C in LDS (aliased over mask buffers)
// and writes out directly with softmax-normalize + ELU. No second pass.
__global__ __launch_bounds__(512, 4) void gat_attn(
    const int* __restrict__ adj, const unsigned short* __restrict__ WhT,
    const float* __restrict__ Wh1, const float* __restrict__ Wh2,
    float* __restrict__ out)
{
    // 36.5 KB: [0,32768) = mask double buffer (2 x 16 rows x 1024 B, swizzled)
    // epilogue aliases: ldsC = 8*16*68*4 = 34816 B @0, ldsT = 512 B @34816
    __shared__ __align__(16) unsigned char smem[35328];
    unsigned char* maskbuf = smem;
    float* ldsC = (float*)smem;                    // [8][16][68]
    float* ldsT = (float*)(smem + 34816);          // [8][16]

    const int tid  = threadIdx.x;
    const int wave = tid >> 6;       // 0..7
    const int lane = tid & 63;
    const int il   = lane & 15;      // A-fragment row (i)
    const int q    = lane >> 4;      // quad -> k offset q*8
    const int i0   = blockIdx.x * 16;
    const int i    = i0 + il;

    const float wh1 = Wh1[i];

    // --- staging role: wave stages rows {2w, 2w+1}, lane covers int4 chunk ---
    const int r0     = wave * 2 + (lane >> 5);   // local row 0..15
    const int cchunk = lane & 31;                // int4 chunk within row
    const int4* __restrict__ arow =
        (const int4*)(adj + (size_t)(i0 + r0) * NN) + cchunk;

    // --- B fragment pointers: f-tiles at rows il, il+16, il+32, il+48 ---
    const short8* bp0 = (const short8*)(WhT + (size_t)(0  + il) * NN);
    const short8* bp1 = (const short8*)(WhT + (size_t)(16 + il) * NN);
    const short8* bp2 = (const short8*)(WhT + (size_t)(32 + il) * NN);
    const short8* bp3 = (const short8*)(WhT + (size_t)(48 + il) * NN);

    f32x4 acc0 = {0.f, 0.f, 0.f, 0.f};
    f32x4 acc1 = {0.f, 0.f, 0.f, 0.f};
    f32x4 acc2 = {0.f, 0.f, 0.f, 0.f};
    f32x4 acc3 = {0.f, 0.f, 0.f, 0.f};
    float tot = 0.f;

    int4 pre[8];

    // prologue: load + store slab 0
#pragma unroll
    for (int k = 0; k < 8; ++k) pre[k] = arow[k * 32];
#pragma unroll
    for (int k = 0; k < 8; ++k) {
        const int4 v = pre[k];
        const unsigned m = ((unsigned)v.x & 1u) | (((unsigned)v.y & 1u) << 8) |
                           (((unsigned)v.z & 1u) << 16) | (((unsigned)v.w & 1u) << 24);
        const int c4 = (cchunk + 32 * k) * 4;
        *(unsigned*)(maskbuf + r0 * 1024 + ((c4 + r0 * 8) & 1023)) = m;
    }
    __syncthreads();

    for (int s = 0; s < 8; ++s) {
        // issue next slab's global loads (latency hidden by compute below)
        if (s < 7) {
#pragma unroll
            for (int k = 0; k < 8; ++k) pre[k] = arow[(s + 1) * 256 + k * 32];
        }

        const unsigned char* mbuf = maskbuf + (s & 1) * 16384;
#pragma unroll
        for (int u = 0; u < 4; ++u) {
            const int c0 = (wave * 4 + u) * 32 + q * 8;   // slab-local col
            const int j  = s * 1024 + c0;                 // global col

            const uint2 mb = *(const uint2*)(mbuf + il * 1024 + ((c0 + il * 8) & 1023));
            const float4 w20 = *(const float4*)(Wh2 + j);
            const float4 w21 = *(const float4*)(Wh2 + j + 4);

            float wv[8];
#define CALC(idx, mword, bit, wh2v)                                    \
            {                                                          \
                float sx = wh1 + (wh2v);                               \
                float e = fmaxf(sx, 0.2f * sx);    /* leaky_relu */    \
                float v = ((mword >> (bit)) & 1u) ? __expf(e) : 0.f;   \
                tot += v;                                              \
                wv[idx] = v;                                           \
            }
            CALC(0, mb.x, 0,  w20.x) CALC(1, mb.x, 8,  w20.y)
            CALC(2, mb.x, 16, w20.z) CALC(3, mb.x, 24, w20.w)
            CALC(4, mb.y, 0,  w21.x) CALC(5, mb.y, 8,  w21.y)
            CALC(6, mb.y, 16, w21.z) CALC(7, mb.y, 24, w21.w)
#undef CALC

            union { short8 v; unsigned int u4[4]; } af;
            af.u4[0] = pack_bf16(wv[0], wv[1]);
            af.u4[1] = pack_bf16(wv[2], wv[3]);
            af.u4[2] = pack_bf16(wv[4], wv[5]);
            af.u4[3] = pack_bf16(wv[6], wv[7]);

            const int jb = j >> 3;
            const short8 b0 = bp0[jb];
            const short8 b1 = bp1[jb];
            const short8 b2 = bp2[jb];
            const short8 b3 = bp3[jb];

            acc0 = __builtin_amdgcn_mfma_f32_16x16x32_bf16(af.v, b0, acc0, 0, 0, 0);
            acc1 = __builtin_amdgcn_mfma_f32_16x16x32_bf16(af.v, b1, acc1, 0, 0, 0);
            acc2 = __builtin_amdgcn_mfma_f32_16x16x32_bf16(af.v, b2, acc2, 0, 0, 0);
            acc3 = __builtin_amdgcn_mfma_f32_16x16x32_bf16(af.v, b3, acc3, 0, 0, 0);
        }

        // pack + store next slab into the other buffer
        if (s < 7) {
            unsigned char* wb = maskbuf + ((s + 1) & 1) * 16384;
#pragma unroll
            for (int k = 0; k < 8; ++k) {
                const int4 v = pre[k];
                const unsigned m = ((unsigned)v.x & 1u) | (((unsigned)v.y & 1u) << 8) |
                                   (((unsigned)v.z & 1u) << 16) | (((unsigned)v.w & 1u) << 24);
                const int c4 = (cchunk + 32 * k) * 4;
                *(unsigned*)(wb + r0 * 1024 + ((c4 + r0 * 8) & 1023)) = m;
            }
        }
        __syncthreads();   // also protects the ldsC alias after the last slab
    }

    // row-total reduction: lanes {il, il+16, il+32, il+48} hold partials
    tot += __shfl_xor(tot, 16, 64);
    tot += __shfl_xor(tot, 32, 64);
    if (lane < 16) ldsT[wave * 16 + lane] = tot;

    // C/D layout: col = lane&15 (f within tile), row = q*4 + reg (i)
#pragma unroll
    for (int r = 0; r < 4; ++r) {
        float* row = ldsC + ((size_t)wave * 16 + (q * 4 + r)) * 68;
        row[0 * 16 + il] = acc0[r];
        row[1 * 16 + il] = acc1[r];
        row[2 * 16 + il] = acc2[r];
        row[3 * 16 + il] = acc3[r];
    }
    __syncthreads();

#pragma unroll
    for (int e = 0; e < 2; ++e) {
        const int idx = e * 512 + tid;       // over 16*64 outputs
        const int ii = idx >> 6;
        const int ff = idx & 63;
        float sC = 0.f, sT = 0.f;
#pragma unroll
        for (int w = 0; w < 8; ++w) {
            sC += ldsC[((size_t)w * 16 + ii) * 68 + ff];
            sT += ldsT[w * 16 + ii];
        }
        const float p = sC / sT;
        out[(size_t)(i0 + ii) * FOUT + ff] = (p > 0.f) ? p : (__expf(p) - 1.f);
    }
}

extern "C" void kernel_launch(void* const* d_in, const int* in_sizes, int n_in,
                              void* d_out, int out_size, void* d_ws, size_t ws_size,
                              hipStream_t stream) {
    const float* x   = (const float*)d_in[0];
    const int*   adj = (const int*)d_in[1];
    const float* W   = (const float*)d_in[2];
    const float* a   = (const float*)d_in[3];
    float* out = (float*)d_out;

    char* ws = (char*)d_ws;
    unsigned short* WhT = (unsigned short*)ws;                 // 1 MB @ 0
    float* Wh1 = (float*)(ws + (size_t)1048576);               // 32 KB
    float* Wh2 = (float*)(ws + (size_t)1048576 + 32768);       // 32 KB

    gat_prep<<<dim3(NN / 4), dim3(256), 0, stream>>>(x, W, a, WhT, Wh1, Wh2);
    gat_attn<<<dim3(NN / 16), dim3(512), 0, stream>>>(adj, WhT, Wh1, Wh2, out);
}